// Round 1
// baseline (1016.052 us; speedup 1.0000x reference)
//
#include <hip/hip_runtime.h>
#include <hip/hip_bf16.h>

// Problem constants: C=256 channels, equirect H=256 x W=512, faces 256x256.
// Padded NHWC conv-input layout: Xp[(H+2)=258 rows][(W+2)=514 cols][256 ch] bf16.
#define NPIX 131072        // 256*512
#define WP   514
#define PPIXN 132612       // 258*514
#define XP_BYTES 67897344  // PPIXN*256*2

typedef __attribute__((ext_vector_type(8))) short bf16x8;  // 8 bf16 = 4 VGPRs
typedef __attribute__((ext_vector_type(4))) float f32x4;

typedef const __attribute__((address_space(1))) void g_cvoid;
typedef __attribute__((address_space(3))) void l_void;

__device__ __forceinline__ void async16(const void* g, void* l) {
  // width-16 global->LDS DMA; LDS dest = wave-uniform base + lane*16
  __builtin_amdgcn_global_load_lds((g_cvoid*)g, (l_void*)l, 16, 0, 0);
}

// ---------------- ws state init (ws is re-poisoned 0xAA before every launch) ---
__global__ void zero_borders(__hip_bfloat16* Xm, __hip_bfloat16* Xa) {
  int i = blockIdx.x;  // 0..1539 border pixels
  __hip_bfloat16* X = blockIdx.y ? Xa : Xm;
  long ppix;
  if (i < 514)       ppix = i;                                  // top row
  else if (i < 1028) ppix = 257L * WP + (i - 514);              // bottom row
  else if (i < 1284) ppix = (long)(i - 1028 + 1) * WP;          // left col
  else               ppix = (long)(i - 1284 + 1) * WP + 513;    // right col
  ((unsigned int*)(X + ppix * 256))[threadIdx.x] = 0u;          // 128 u32 = 256 bf16
}

__global__ void zero_mask(float* maskacc) {
  maskacc[blockIdx.x * 256 + threadIdx.x] = 0.f;
}

// Wf [cout][cin][3][3] fp32 -> Wt [cout][(ky*3+kx)*256+ci] bf16  (B^T, k-contiguous)
__global__ void prep_weights(const float* __restrict__ Wf, __hip_bfloat16* __restrict__ Wt) {
  int idx = blockIdx.x * 256 + threadIdx.x;   // 589824 total
  int cout = idx / 2304, rem = idx % 2304;
  int o = rem >> 8, ci = rem & 255;
  Wt[idx] = __float2bfloat16(Wf[(cout * 256 + ci) * 9 + o]);
}

// ---------------- cube2equi geometry (per pixel, once) -------------------------
__global__ void geom_kernel(float4* __restrict__ geom) {
  int p = blockIdx.x * 256 + threadIdx.x;   // 131072
  int yy = p >> 9, xx = p & 511;
  float theta = ((xx + 0.5f) / 512.f) * 6.283185307179586f - 3.141592653589793f;
  float phi   = 1.5707963267948966f - ((yy + 0.5f) / 256.f) * 3.141592653589793f;
  float st = sinf(theta), ct = cosf(theta);
  float sp = sinf(phi),   cp = cosf(phi);
  float dx = cp * st, dy = sp, dz = cp * ct;
  float ax = fabsf(dx), ay = fabsf(dy), az = fabsf(dz);
  float mx = fmaxf(fmaxf(ax, ay), az);
  float pxn = dx / mx, pyn = dy / mx, pzn = dz / mx;
  bool cz = (az >= ax) && (az >= ay);
  bool cx = (!cz) && (ax >= ay);
  int face; float a, b;
  if (cz)      { face = dz > 0.f ? 2 : 0; a = dz > 0.f ? pxn : -pxn; b = -pyn; }
  else if (cx) { face = dx > 0.f ? 4 : 3; a = dx > 0.f ? -pzn : pzn; b = -pyn; }
  else         { face = dy > 0.f ? 5 : 1; a = pxn; b = dy > 0.f ? pzn : -pzn; }
  float uu = fminf(fmaxf((a + 1.f) * 0.5f * 255.f, 0.f), 255.f);
  float vv = fminf(fmaxf((b + 1.f) * 0.5f * 255.f, 0.f), 255.f);
  geom[p] = make_float4(uu, vv, (float)face, 0.f);
}

// ---------------- m (NCHW fp32) -> padded NHWC bf16 ----------------------------
__global__ void nchw_to_pad_nhwc(const float* __restrict__ src, __hip_bfloat16* __restrict__ Xp) {
  __shared__ __align__(16) __hip_bfloat16 tile[64 * 264];  // 64 px x 256 ch (+8 pad)
  int tid = threadIdx.x;
  int p0 = blockIdx.x * 64;
  int px = tid & 63, w = tid >> 6;
  for (int k = 0; k < 64; ++k) {
    int c = (k << 2) + w;
    tile[px * 264 + c] = __float2bfloat16(src[(long)c * NPIX + p0 + px]);
  }
  __syncthreads();
  int y = p0 >> 9, x0 = p0 & 511;
  long basep = (long)(y + 1) * WP + x0 + 1;
  for (int pass = 0; pass < 8; ++pass) {
    int tpx = (pass << 3) + (tid >> 5);
    int chunk = tid & 31;
    uint4 v = *(const uint4*)&tile[tpx * 264 + (chunk << 3)];
    *(uint4*)&Xp[(basep + tpx) * 256 + (chunk << 3)] = v;
  }
}

// ---------------- cube2equi sampling -> padded NHWC bf16 -----------------------
// faces: 0 -> b, 1 -> d, 5 -> u, {2,3,4} -> zero
__global__ void aux_gen(const float* __restrict__ fb, const float* __restrict__ fd,
                        const float* __restrict__ fu, const float4* __restrict__ geom,
                        __hip_bfloat16* __restrict__ Xp) {
  __shared__ __align__(16) __hip_bfloat16 tile[64 * 264];
  __shared__ float4 sg[64];
  int tid = threadIdx.x;
  int p0 = blockIdx.x * 64;
  if (tid < 64) sg[tid] = geom[p0 + tid];
  __syncthreads();
  int px = tid & 63, w = tid >> 6;
  float4 g = sg[px];
  int face = (int)g.z;
  const float* F = (face == 0) ? fb : (face == 1) ? fd : (face == 5) ? fu : nullptr;
  int u0 = (int)g.x, v0 = (int)g.y;           // floor (nonneg, clipped)
  int u1 = min(u0 + 1, 255), v1 = min(v0 + 1, 255);
  float wu = g.x - (float)u0, wv = g.y - (float)v0;
  float w00 = (1.f - wv) * (1.f - wu), w01 = (1.f - wv) * wu;
  float w10 = wv * (1.f - wu),         w11 = wv * wu;
  int i00 = v0 * 256 + u0, i01 = v0 * 256 + u1;
  int i10 = v1 * 256 + u0, i11 = v1 * 256 + u1;
  for (int k = 0; k < 64; ++k) {
    int c = (k << 2) + w;
    float val = 0.f;
    if (F) {
      const float* Fc = F + ((long)c << 16);
      val = w00 * Fc[i00] + w01 * Fc[i01] + w10 * Fc[i10] + w11 * Fc[i11];
    }
    tile[px * 264 + c] = __float2bfloat16(val);
  }
  __syncthreads();
  int y = p0 >> 9, x0 = p0 & 511;
  long basep = (long)(y + 1) * WP + x0 + 1;
  for (int pass = 0; pass < 8; ++pass) {
    int tpx = (pass << 3) + (tid >> 5);
    int chunk = tid & 31;
    uint4 v = *(const uint4*)&tile[tpx * 264 + (chunk << 3)];
    *(uint4*)&Xp[(basep + tpx) * 256 + (chunk << 3)] = v;
  }
}

// ---------------- 3x3 conv as implicit GEMM (MFMA bf16) ------------------------
// D[pix][cout] = sum_k Xp[pix+off(k)][ci(k)] * Wt[cout][k], K = 9*256
// 128 pix x 128 cout per block, BK=32, 4 waves each 64x64 (4x4 MFMA 16x16x32).
// Epilogue: +bias, relu, optional store (NHWC bf16), fused 1x1 mask-dot -> atomicAdd.
template <bool STORE>
__global__ void conv3x3_mfma(const __hip_bfloat16* __restrict__ Xp,
                             const __hip_bfloat16* __restrict__ Wt,
                             const float* __restrict__ bias,
                             const float* __restrict__ wm,
                             __hip_bfloat16* __restrict__ Out,
                             float* __restrict__ maskacc) {
  __shared__ __align__(16) __hip_bfloat16 At[128 * 32];
  __shared__ __align__(16) __hip_bfloat16 Bt[128 * 32];
  const int tid = threadIdx.x;
  const int wave = tid >> 6, lane = tid & 63;
  const int p0 = blockIdx.x * 128;   // pixel tile (all same image row; 128|512)
  const int n0 = blockIdx.y * 128;   // cout tile
  const int y = p0 >> 9, x0 = p0 & 511;
  const int lrow = lane >> 2;        // 16 rows per wave-instruction
  const int lci  = (lane & 3) << 3;  // 8-elem (16B) column chunk
  const int m_off = (wave >> 1) << 6;
  const int n_off = (wave & 1) << 6;
  const int lq = lane >> 4;          // quad
  const int ln = lane & 15;

  f32x4 acc[4][4] = {};

  for (int s = 0; s < 72; ++s) {
    const int o = s >> 3;
    const int ci0 = (s & 7) << 5;
    const int dy = o / 3 - 1, dx = o % 3 - 1;
    const long prow = (long)(y + 1 + dy) * WP + (x0 + 1 + dx);
#pragma unroll
    for (int i = 0; i < 2; ++i) {     // A: wave stages pixel rows [32w, 32w+32)
      int pxb = (wave << 5) + (i << 4);
      const __hip_bfloat16* gp = Xp + ((prow + pxb + lrow) << 8) + ci0 + lci;
      async16(gp, &At[pxb * 32]);
    }
    const int k0 = s << 5;
#pragma unroll
    for (int i = 0; i < 2; ++i) {     // B: wave stages cout rows [32w, 32w+32)
      int nb = (wave << 5) + (i << 4);
      const __hip_bfloat16* gp = Wt + (long)(n0 + nb + lrow) * 2304 + k0 + lci;
      async16(gp, &Bt[nb * 32]);
    }
    __syncthreads();   // barrier drains vmcnt -> staged data visible
    bf16x8 af[4], bb[4];
#pragma unroll
    for (int mi = 0; mi < 4; ++mi)
      af[mi] = *(const bf16x8*)&At[(m_off + mi * 16 + ln) * 32 + (lq << 3)];
#pragma unroll
    for (int ni = 0; ni < 4; ++ni)
      bb[ni] = *(const bf16x8*)&Bt[(n_off + ni * 16 + ln) * 32 + (lq << 3)];
#pragma unroll
    for (int mi = 0; mi < 4; ++mi)
#pragma unroll
      for (int ni = 0; ni < 4; ++ni)
        acc[mi][ni] = __builtin_amdgcn_mfma_f32_16x16x32_bf16(af[mi], bb[ni], acc[mi][ni], 0, 0, 0);
    __syncthreads();
  }

  // epilogue: bias + relu (+store NHWC bf16) + fused mask 1x1 dot
  float bv[4], wv[4];
#pragma unroll
  for (int ni = 0; ni < 4; ++ni) {
    int cc = n0 + n_off + ni * 16 + ln;
    bv[ni] = bias[cc];
    wv[ni] = wm[cc];
  }
#pragma unroll
  for (int mi = 0; mi < 4; ++mi) {
#pragma unroll
    for (int r = 0; r < 4; ++r) {
      int pix = p0 + m_off + mi * 16 + (lq << 2) + r;   // D row = pixel
      float mp = 0.f;
#pragma unroll
      for (int ni = 0; ni < 4; ++ni) {
        float v = acc[mi][ni][r] + bv[ni];
        v = v > 0.f ? v : 0.f;
        if (STORE) Out[((long)pix << 8) + (n0 + n_off + ni * 16 + ln)] = __float2bfloat16(v);
        mp += v * wv[ni];
      }
      mp += __shfl_xor(mp, 1);
      mp += __shfl_xor(mp, 2);
      mp += __shfl_xor(mp, 4);
      mp += __shfl_xor(mp, 8);
      if (ln == 0) atomicAdd(&maskacc[pix], mp);
    }
  }
}

// ---------------- mask sigmoid + final combine ---------------------------------
__global__ void mask_sigmoid(float* maskacc, const float* __restrict__ bm) {
  int i = blockIdx.x * 256 + threadIdx.x;
  float v = maskacc[i] + bm[0];
  maskacc[i] = 1.f / (1.f + expf(-v));
}

// out[c][p] = m[c][p] + mask[p] * M_aux_t[p][c]   (NCHW out; aux tile L1-resident)
__global__ void final_combine(const float* __restrict__ m,
                              const __hip_bfloat16* __restrict__ MauxT,
                              const float* __restrict__ mask,
                              float* __restrict__ out) {
  __shared__ float sm[64];
  int tid = threadIdx.x;
  int p0 = blockIdx.x * 64;
  if (tid < 64) sm[tid] = mask[p0 + tid];
  __syncthreads();
  int px = tid & 63, w = tid >> 6;
  float mk = sm[px];
  for (int k = 0; k < 64; ++k) {
    int c = (k << 2) + w;
    long gi = (long)c * NPIX + p0 + px;
    float aux = __bfloat162float(MauxT[((long)(p0 + px) << 8) + c]);
    out[gi] = m[gi] + mk * aux;
  }
}

extern "C" void kernel_launch(void* const* d_in, const int* in_sizes, int n_in,
                              void* d_out, int out_size, void* d_ws, size_t ws_size,
                              hipStream_t stream) {
  const float* m  = (const float*)d_in[0];
  const float* fb = (const float*)d_in[1];  // face 0 (back)
  const float* fu = (const float*)d_in[2];  // face 5 (up)
  const float* fd = (const float*)d_in[3];  // face 1 (down)
  const float* Wf = (const float*)d_in[4];
  const float* bf = (const float*)d_in[5];
  const float* Wm = (const float*)d_in[6];
  const float* bm = (const float*)d_in[7];
  float* out = (float*)d_out;

  char* ws = (char*)d_ws;
  __hip_bfloat16* Xp_m   = (__hip_bfloat16*)(ws);
  __hip_bfloat16* Xp_aux = (__hip_bfloat16*)(ws + (size_t)XP_BYTES);
  __hip_bfloat16* Wt     = (__hip_bfloat16*)(ws + 2uL * XP_BYTES);
  __hip_bfloat16* MauxT  = (__hip_bfloat16*)(ws + 2uL * XP_BYTES + 1179648);
  float* maskacc         = (float*)(ws + 2uL * XP_BYTES + 1179648 + 67108864);
  float4* geom           = (float4*)(ws + 2uL * XP_BYTES + 1179648 + 67108864 + 524288);
  // total ws use: ~197 MiB

  zero_borders<<<dim3(1540, 2), 128, 0, stream>>>(Xp_m, Xp_aux);
  zero_mask<<<512, 256, 0, stream>>>(maskacc);
  prep_weights<<<2304, 256, 0, stream>>>(Wf, Wt);
  geom_kernel<<<512, 256, 0, stream>>>(geom);
  nchw_to_pad_nhwc<<<2048, 256, 0, stream>>>(m, Xp_m);
  aux_gen<<<2048, 256, 0, stream>>>(fb, fd, fu, geom, Xp_aux);
  // aux conv: stores M_aux (NHWC bf16) + mask contribution (Wm[256:512])
  conv3x3_mfma<true><<<dim3(1024, 2), 256, 0, stream>>>(Xp_aux, Wt, bf, Wm + 256, MauxT, maskacc);
  // main conv: mask contribution only (Wm[0:256]); M_main never materialized
  conv3x3_mfma<false><<<dim3(1024, 2), 256, 0, stream>>>(Xp_m, Wt, bf, Wm, nullptr, maskacc);
  mask_sigmoid<<<512, 256, 0, stream>>>(maskacc, bm);
  final_combine<<<2048, 256, 0, stream>>>(m, MauxT, maskacc, out);
}

// Round 2
// 832.679 us; speedup vs baseline: 1.2202x; 1.2202x over previous
//
#include <hip/hip_runtime.h>
#include <hip/hip_bf16.h>

// Problem constants: C=256 channels, equirect H=256 x W=512, faces 256x256.
// Padded NHWC conv-input layout: Xp[(H+2)=258 rows][(W+2)=514 cols][256 ch] bf16.
#define NPIX 131072        // 256*512
#define WP   514
#define XP_BYTES 67897344  // 258*514*256*2
#define XP_STRIDE 67962880 // XP_BYTES + 64KB slack (conv halo staging over-reads up to 7KB)

typedef __attribute__((ext_vector_type(8))) short bf16x8;  // 8 bf16 = 4 VGPRs
typedef __attribute__((ext_vector_type(4))) float f32x4;

typedef const __attribute__((address_space(1))) void g_cvoid;
typedef __attribute__((address_space(3))) void l_void;

__device__ __forceinline__ void async16(const void* g, void* l) {
  // width-16 global->LDS DMA; LDS dest = wave-uniform base + lane*16
  __builtin_amdgcn_global_load_lds((g_cvoid*)g, (l_void*)l, 16, 0, 0);
}

// ---------------- ws state init (ws is re-poisoned 0xAA before every launch) ---
__global__ void zero_borders(__hip_bfloat16* Xm, __hip_bfloat16* Xa) {
  int i = blockIdx.x;  // 0..1539 border pixels
  __hip_bfloat16* X = blockIdx.y ? Xa : Xm;
  long ppix;
  if (i < 514)       ppix = i;                                  // top row
  else if (i < 1028) ppix = 257L * WP + (i - 514);              // bottom row
  else if (i < 1284) ppix = (long)(i - 1028 + 1) * WP;          // left col
  else               ppix = (long)(i - 1284 + 1) * WP + 513;    // right col
  ((unsigned int*)(X + ppix * 256))[threadIdx.x] = 0u;          // 128 u32 = 256 bf16
}

__global__ void zero_mask(float* maskacc) {
  maskacc[blockIdx.x * 256 + threadIdx.x] = 0.f;
}

// Wf [cout][cin][3][3] fp32 -> Wtt [(o*32 + ci>>3)][cout][ci&7] bf16
// so a B fragment (quad lq, lane ln) reads 256B-contiguous, coalesced b128.
__global__ void prep_weights(const float* __restrict__ Wf, __hip_bfloat16* __restrict__ Wtt) {
  int idx = blockIdx.x * 256 + threadIdx.x;   // 589824 total
  int cout = idx / 2304, rem = idx % 2304;
  int o = rem >> 8, ci = rem & 255;
  Wtt[(((o << 5) + (ci >> 3)) << 11) + (cout << 3) + (ci & 7)] =
      __float2bfloat16(Wf[(cout * 256 + ci) * 9 + o]);
}

// ---------------- m (NCHW fp32) -> padded NHWC bf16 ----------------------------
__global__ void nchw_to_pad_nhwc(const float* __restrict__ src, __hip_bfloat16* __restrict__ Xp) {
  __shared__ __align__(16) __hip_bfloat16 tile[64 * 264];  // 64 px x 256 ch (+8 pad)
  int tid = threadIdx.x;
  int p0 = blockIdx.x * 64;
  int px = tid & 63, w = tid >> 6;
  for (int k = 0; k < 64; ++k) {
    int c = (k << 2) + w;
    tile[px * 264 + c] = __float2bfloat16(src[(long)c * NPIX + p0 + px]);
  }
  __syncthreads();
  int y = p0 >> 9, x0 = p0 & 511;
  long basep = (long)(y + 1) * WP + x0 + 1;
  for (int pass = 0; pass < 8; ++pass) {
    int tpx = (pass << 3) + (tid >> 5);
    int chunk = tid & 31;
    uint4 v = *(const uint4*)&tile[tpx * 264 + (chunk << 3)];
    *(uint4*)&Xp[(basep + tpx) * 256 + (chunk << 3)] = v;
  }
}

// ---------------- cube2equi sampling -> padded NHWC bf16 -----------------------
// faces: 0 -> b, 1 -> d, 5 -> u, {2,3,4} -> zero. Geometry inlined per thread.
__global__ void aux_gen(const float* __restrict__ fb, const float* __restrict__ fd,
                        const float* __restrict__ fu,
                        __hip_bfloat16* __restrict__ Xp) {
  __shared__ __align__(16) __hip_bfloat16 tile[64 * 264];
  int tid = threadIdx.x;
  int p0 = blockIdx.x * 64;
  int px = tid & 63, w = tid >> 6;

  int p = p0 + px;
  int yy = p >> 9, xx = p & 511;
  float theta = ((xx + 0.5f) / 512.f) * 6.283185307179586f - 3.141592653589793f;
  float phi   = 1.5707963267948966f - ((yy + 0.5f) / 256.f) * 3.141592653589793f;
  float st = sinf(theta), ct = cosf(theta);
  float sp = sinf(phi),   cp = cosf(phi);
  float dx = cp * st, dy = sp, dz = cp * ct;
  float ax = fabsf(dx), ay = fabsf(dy), az = fabsf(dz);
  float mx = fmaxf(fmaxf(ax, ay), az);
  float pxn = dx / mx, pyn = dy / mx, pzn = dz / mx;
  bool cz = (az >= ax) && (az >= ay);
  bool cx = (!cz) && (ax >= ay);
  int face; float a, b;
  if (cz)      { face = dz > 0.f ? 2 : 0; a = dz > 0.f ? pxn : -pxn; b = -pyn; }
  else if (cx) { face = dx > 0.f ? 4 : 3; a = dx > 0.f ? -pzn : pzn; b = -pyn; }
  else         { face = dy > 0.f ? 5 : 1; a = pxn; b = dy > 0.f ? pzn : -pzn; }
  float uu = fminf(fmaxf((a + 1.f) * 0.5f * 255.f, 0.f), 255.f);
  float vv = fminf(fmaxf((b + 1.f) * 0.5f * 255.f, 0.f), 255.f);

  const float* F = (face == 0) ? fb : (face == 1) ? fd : (face == 5) ? fu : nullptr;
  int u0 = (int)uu, v0 = (int)vv;
  int u1 = min(u0 + 1, 255), v1 = min(v0 + 1, 255);
  float wu = uu - (float)u0, wv = vv - (float)v0;
  float w00 = (1.f - wv) * (1.f - wu), w01 = (1.f - wv) * wu;
  float w10 = wv * (1.f - wu),         w11 = wv * wu;
  int i00 = v0 * 256 + u0, i01 = v0 * 256 + u1;
  int i10 = v1 * 256 + u0, i11 = v1 * 256 + u1;
  for (int k = 0; k < 64; ++k) {
    int c = (k << 2) + w;
    float val = 0.f;
    if (F) {
      const float* Fc = F + ((long)c << 16);
      val = w00 * Fc[i00] + w01 * Fc[i01] + w10 * Fc[i10] + w11 * Fc[i11];
    }
    tile[px * 264 + c] = __float2bfloat16(val);
  }
  __syncthreads();
  int y = p0 >> 9, x0g = p0 & 511;
  long basep = (long)(y + 1) * WP + x0g + 1;
  for (int pass = 0; pass < 8; ++pass) {
    int tpx = (pass << 3) + (tid >> 5);
    int chunk = tid & 31;
    uint4 v = *(const uint4*)&tile[tpx * 264 + (chunk << 3)];
    *(uint4*)&Xp[(basep + tpx) * 256 + (chunk << 3)] = v;
  }
}

// ---------------- 3x3 conv as implicit GEMM (MFMA bf16) ------------------------
// Tile: 2 pixel rows x 64 cols (M=128) x 128 cout. K-loop: ci-slice outer (8),
// stage 4-row x 80-col x 32-ch halo in LDS once, then 9 taps x 16 MFMA from LDS.
// B fragments: direct global b128 from Wtt (coalesced, L2-resident, no barrier).
// Epilogue: +bias, relu, optional NHWC bf16 store, fused 1x1 mask-dot atomicAdd.
template <bool STORE>
__global__ void conv3x3_mfma(const __hip_bfloat16* __restrict__ Xp,
                             const __hip_bfloat16* __restrict__ Wtt,
                             const float* __restrict__ bias,
                             const float* __restrict__ wm,
                             __hip_bfloat16* __restrict__ Out,
                             float* __restrict__ maskacc) {
  __shared__ __align__(16) __hip_bfloat16 At[4 * 80 * 32];   // 20480 B halo
  const int tid = threadIdx.x;
  const int wave = tid >> 6, lane = tid & 63;
  const int bx = blockIdx.x;
  const int n0 = (bx & 1) << 7;        // cout half
  const int tile = bx >> 1;            // 0..1023
  const int x0 = (tile >> 7) << 6;     // col strip (8 strips of 64)
  const int y0 = (tile & 127) << 1;    // row pair (rows vary fastest -> halo reuse)
  const int wrow = wave >> 1;          // this wave's pixel row within tile (0/1)
  const int n_off = (wave & 1) << 6;   // this wave's cout offset (0/64)
  const int lq = lane >> 4, ln = lane & 15;

  // halo staging: wave stages padded row (y0 + wave), cols x0 .. x0+79
  const long stage_row = (long)(y0 + wave) * WP + x0;
  const int s_col = lane >> 2;           // 0..15
  const int s_ci  = (lane & 3) << 3;     // 0,8,16,24

  f32x4 acc[4][4] = {};   // [mi (16-px col group)][ni (16-cout group)]

  for (int s = 0; s < 8; ++s) {
    const int ci0 = s << 5;
#pragma unroll
    for (int j = 0; j < 5; ++j) {
      const __hip_bfloat16* gp = Xp + ((stage_row + (j << 4) + s_col) << 8) + ci0 + s_ci;
      async16(gp, &At[(wave * 80 + (j << 4)) << 5]);
    }
    __syncthreads();   // drains vmcnt -> staged halo visible
#pragma unroll
    for (int o = 0; o < 9; ++o) {
      const int dy = o / 3, dxo = o % 3;
      const int arow = (wrow + dy) * 80;
      bf16x8 af[4], bb[4];
#pragma unroll
      for (int mi = 0; mi < 4; ++mi)
        af[mi] = *(const bf16x8*)&At[((arow + mi * 16 + ln + dxo) << 5) + (lq << 3)];
#pragma unroll
      for (int ni = 0; ni < 4; ++ni)
        bb[ni] = *(const bf16x8*)&Wtt[(((o << 5) + (s << 2) + lq) << 11) +
                                      ((n0 + n_off + ni * 16 + ln) << 3)];
#pragma unroll
      for (int mi = 0; mi < 4; ++mi)
#pragma unroll
        for (int ni = 0; ni < 4; ++ni)
          acc[mi][ni] = __builtin_amdgcn_mfma_f32_16x16x32_bf16(af[mi], bb[ni], acc[mi][ni], 0, 0, 0);
    }
    __syncthreads();   // protect At before next slice's staging
  }

  // epilogue: bias + relu (+store NHWC bf16) + fused mask 1x1 dot
  float bv[4], wv[4];
#pragma unroll
  for (int ni = 0; ni < 4; ++ni) {
    int cc = n0 + n_off + ni * 16 + ln;
    bv[ni] = bias[cc];
    wv[ni] = wm[cc];
  }
  const int prow = (y0 + wrow) * 512 + x0;
#pragma unroll
  for (int mi = 0; mi < 4; ++mi) {
#pragma unroll
    for (int r = 0; r < 4; ++r) {
      int pix = prow + mi * 16 + (lq << 2) + r;   // D row = pixel col within tile
      float mp = 0.f;
#pragma unroll
      for (int ni = 0; ni < 4; ++ni) {
        float v = acc[mi][ni][r] + bv[ni];
        v = v > 0.f ? v : 0.f;
        if (STORE) Out[((long)pix << 8) + (n0 + n_off + ni * 16 + ln)] = __float2bfloat16(v);
        mp += v * wv[ni];
      }
      mp += __shfl_xor(mp, 1);
      mp += __shfl_xor(mp, 2);
      mp += __shfl_xor(mp, 4);
      mp += __shfl_xor(mp, 8);
      if (ln == 0) atomicAdd(&maskacc[pix], mp);
    }
  }
}

// ---------------- mask sigmoid + final combine ---------------------------------
__global__ void mask_sigmoid(float* maskacc, const float* __restrict__ bm) {
  int i = blockIdx.x * 256 + threadIdx.x;
  float v = maskacc[i] + bm[0];
  maskacc[i] = 1.f / (1.f + expf(-v));
}

// out[c][p] = m[c][p] + mask[p] * M_aux_t[p][c]; aux transposed through LDS
__global__ void final_combine(const float* __restrict__ m,
                              const __hip_bfloat16* __restrict__ MauxT,
                              const float* __restrict__ mask,
                              float* __restrict__ out) {
  __shared__ __align__(16) __hip_bfloat16 tile[64 * 264];
  __shared__ float sm[64];
  int tid = threadIdx.x;
  int p0 = blockIdx.x * 64;
  if (tid < 64) sm[tid] = mask[p0 + tid];
#pragma unroll
  for (int j = 0; j < 8; ++j) {       // stage 64 px x 256 ch, coalesced uint4
    int f = j * 256 + tid;            // 0..2047
    int px = f >> 5, c8 = f & 31;
    *(uint4*)&tile[px * 264 + (c8 << 3)] =
        *(const uint4*)&MauxT[(((long)(p0 + px)) << 8) + (c8 << 3)];
  }
  __syncthreads();
  int px = tid & 63, w = tid >> 6;
  float mk = sm[px];
  for (int k = 0; k < 64; ++k) {
    int c = (k << 2) + w;
    long gi = (long)c * NPIX + p0 + px;
    out[gi] = m[gi] + mk * __bfloat162float(tile[px * 264 + c]);
  }
}

extern "C" void kernel_launch(void* const* d_in, const int* in_sizes, int n_in,
                              void* d_out, int out_size, void* d_ws, size_t ws_size,
                              hipStream_t stream) {
  const float* m  = (const float*)d_in[0];
  const float* fb = (const float*)d_in[1];  // face 0 (back)
  const float* fu = (const float*)d_in[2];  // face 5 (up)
  const float* fd = (const float*)d_in[3];  // face 1 (down)
  const float* Wf = (const float*)d_in[4];
  const float* bf = (const float*)d_in[5];
  const float* Wm = (const float*)d_in[6];
  const float* bm = (const float*)d_in[7];
  float* out = (float*)d_out;

  char* ws = (char*)d_ws;
  __hip_bfloat16* Xp_m   = (__hip_bfloat16*)(ws);
  __hip_bfloat16* Xp_aux = (__hip_bfloat16*)(ws + (size_t)XP_STRIDE);
  __hip_bfloat16* Wtt    = (__hip_bfloat16*)(ws + 2uL * XP_STRIDE);
  __hip_bfloat16* MauxT  = (__hip_bfloat16*)(ws + 2uL * XP_STRIDE + 1179648);
  float* maskacc         = (float*)(ws + 2uL * XP_STRIDE + 1179648 + 67108864);
  // total ws use: ~195.3 MiB

  zero_borders<<<dim3(1540, 2), 128, 0, stream>>>(Xp_m, Xp_aux);
  zero_mask<<<512, 256, 0, stream>>>(maskacc);
  prep_weights<<<2304, 256, 0, stream>>>(Wf, Wtt);
  nchw_to_pad_nhwc<<<2048, 256, 0, stream>>>(m, Xp_m);
  aux_gen<<<2048, 256, 0, stream>>>(fb, fd, fu, Xp_aux);
  // aux conv: stores M_aux (NHWC bf16) + mask contribution (Wm[256:512])
  conv3x3_mfma<true><<<2048, 256, 0, stream>>>(Xp_aux, Wtt, bf, Wm + 256, MauxT, maskacc);
  // main conv: mask contribution only (Wm[0:256]); M_main never materialized
  conv3x3_mfma<false><<<2048, 256, 0, stream>>>(Xp_m, Wtt, bf, Wm, nullptr, maskacc);
  mask_sigmoid<<<512, 256, 0, stream>>>(maskacc, bm);
  final_combine<<<2048, 256, 0, stream>>>(m, MauxT, maskacc, out);
}

// Round 3
// 755.217 us; speedup vs baseline: 1.3454x; 1.1026x over previous
//
#include <hip/hip_runtime.h>
#include <hip/hip_bf16.h>

// Problem constants: C=256 channels, equirect H=256 x W=512, faces 256x256.
// Padded NHWC conv-input layout: Xp[(H+2)=258 rows][(W+2)=514 cols][256 ch] bf16.
#define NPIX 131072        // 256*512
#define WP   514
#define XP_BYTES 67897344  // 258*514*256*2
#define XP_STRIDE 67962880 // XP_BYTES + 64KB slack (conv halo staging over-reads up to 7KB)
#define FT_BYTES 100663296 // 3 faces * 65536 px * 256 ch * 2B (NHWC bf16)

typedef __attribute__((ext_vector_type(8))) short bf16x8;  // 8 bf16 = 4 VGPRs
typedef __attribute__((ext_vector_type(4))) float f32x4;

typedef const __attribute__((address_space(1))) void g_cvoid;
typedef __attribute__((address_space(3))) void l_void;

__device__ __forceinline__ void async16(const void* g, void* l) {
  // width-16 global->LDS DMA; LDS dest = wave-uniform base + lane*16
  __builtin_amdgcn_global_load_lds((g_cvoid*)g, (l_void*)l, 16, 0, 0);
}

// ---------------- ws state init (ws is re-poisoned 0xAA before every launch) ---
__global__ void zero_borders(__hip_bfloat16* Xm, __hip_bfloat16* Xa) {
  int i = blockIdx.x;  // 0..1539 border pixels
  __hip_bfloat16* X = blockIdx.y ? Xa : Xm;
  long ppix;
  if (i < 514)       ppix = i;                                  // top row
  else if (i < 1028) ppix = 257L * WP + (i - 514);              // bottom row
  else if (i < 1284) ppix = (long)(i - 1028 + 1) * WP;          // left col
  else               ppix = (long)(i - 1284 + 1) * WP + 513;    // right col
  ((unsigned int*)(X + ppix * 256))[threadIdx.x] = 0u;          // 128 u32 = 256 bf16
}

__global__ void zero_mask(float* maskacc) {
  maskacc[blockIdx.x * 256 + threadIdx.x] = 0.f;
}

// Wf [cout][cin][3][3] fp32 -> Wtt [(o*32 + ci>>3)][cout][ci&7] bf16
// so a B fragment (quad lq, lane ln) reads 256B-contiguous, coalesced b128.
__global__ void prep_weights(const float* __restrict__ Wf, __hip_bfloat16* __restrict__ Wtt) {
  int idx = blockIdx.x * 256 + threadIdx.x;   // 589824 total
  int cout = idx / 2304, rem = idx % 2304;
  int o = rem >> 8, ci = rem & 255;
  Wtt[(((o << 5) + (ci >> 3)) << 11) + (cout << 3) + (ci & 7)] =
      __float2bfloat16(Wf[(cout * 256 + ci) * 9 + o]);
}

// ---------------- m (NCHW fp32) -> padded NHWC bf16 ----------------------------
__global__ void nchw_to_pad_nhwc(const float* __restrict__ src, __hip_bfloat16* __restrict__ Xp) {
  __shared__ __align__(16) __hip_bfloat16 tile[64 * 264];  // 64 px x 256 ch (+8 pad)
  int tid = threadIdx.x;
  int p0 = blockIdx.x * 64;
  int px = tid & 63, w = tid >> 6;
  for (int k = 0; k < 64; ++k) {
    int c = (k << 2) + w;
    tile[px * 264 + c] = __float2bfloat16(src[(long)c * NPIX + p0 + px]);
  }
  __syncthreads();
  int y = p0 >> 9, x0 = p0 & 511;
  long basep = (long)(y + 1) * WP + x0 + 1;
  for (int pass = 0; pass < 8; ++pass) {
    int tpx = (pass << 3) + (tid >> 5);
    int chunk = tid & 31;
    uint4 v = *(const uint4*)&tile[tpx * 264 + (chunk << 3)];
    *(uint4*)&Xp[(basep + tpx) * 256 + (chunk << 3)] = v;
  }
}

// ---------------- faces (NCHW fp32, 3 used faces) -> NHWC bf16 -----------------
__global__ void face_to_nhwc(const float* __restrict__ fb, const float* __restrict__ fd,
                             const float* __restrict__ fu, __hip_bfloat16* __restrict__ Ft) {
  __shared__ __align__(16) __hip_bfloat16 tile[64 * 264];
  int tid = threadIdx.x;
  int face = blockIdx.x >> 10;         // 0..2 (slot: 0=b,1=d,2=u)
  int p0 = (blockIdx.x & 1023) << 6;
  const float* src = (face == 0) ? fb : (face == 1) ? fd : fu;
  int px = tid & 63, w = tid >> 6;
  for (int k = 0; k < 64; ++k) {
    int c = (k << 2) + w;
    tile[px * 264 + c] = __float2bfloat16(src[(long)c * 65536 + p0 + px]);
  }
  __syncthreads();
  long basep = ((long)face << 16) + p0;
  for (int pass = 0; pass < 8; ++pass) {
    int tpx = (pass << 3) + (tid >> 5);
    int chunk = tid & 31;
    uint4 v = *(const uint4*)&tile[tpx * 264 + (chunk << 3)];
    *(uint4*)&Ft[((basep + tpx) << 8) + (chunk << 3)] = v;
  }
}

// ---------------- cube2equi sampling v2: one wave per output pixel -------------
// Ft is NHWC bf16: sample = 512B contiguous. Lane parity = u0/u1, lane>>1 = ch octet.
__device__ __forceinline__ void bf8_fma(uint4 q, float w, float* acc) {
  unsigned x;
  x = q.x; acc[0] += w * __uint_as_float(x << 16); acc[1] += w * __uint_as_float(x & 0xffff0000u);
  x = q.y; acc[2] += w * __uint_as_float(x << 16); acc[3] += w * __uint_as_float(x & 0xffff0000u);
  x = q.z; acc[4] += w * __uint_as_float(x << 16); acc[5] += w * __uint_as_float(x & 0xffff0000u);
  x = q.w; acc[6] += w * __uint_as_float(x << 16); acc[7] += w * __uint_as_float(x & 0xffff0000u);
}

__global__ void aux_gen_v2(const __hip_bfloat16* __restrict__ Ft,
                           __hip_bfloat16* __restrict__ Xp) {
  const int lane = threadIdx.x & 63;
  const int p = (blockIdx.x << 2) + (threadIdx.x >> 6);  // one wave per pixel
  const int yy = p >> 9, xx = p & 511;

  // geometry (wave-uniform; each lane computes the same values)
  float theta = ((xx + 0.5f) / 512.f) * 6.283185307179586f - 3.141592653589793f;
  float phi   = 1.5707963267948966f - ((yy + 0.5f) / 256.f) * 3.141592653589793f;
  float st = sinf(theta), ct = cosf(theta);
  float sp = sinf(phi),   cp = cosf(phi);
  float dx = cp * st, dy = sp, dz = cp * ct;
  float ax = fabsf(dx), ay = fabsf(dy), az = fabsf(dz);
  float mx = fmaxf(fmaxf(ax, ay), az);
  float pxn = dx / mx, pyn = dy / mx, pzn = dz / mx;
  bool cz = (az >= ax) && (az >= ay);
  bool cx = (!cz) && (ax >= ay);
  int face; float a, b;
  if (cz)      { face = dz > 0.f ? 2 : 0; a = dz > 0.f ? pxn : -pxn; b = -pyn; }
  else if (cx) { face = dx > 0.f ? 4 : 3; a = dx > 0.f ? -pzn : pzn; b = -pyn; }
  else         { face = dy > 0.f ? 5 : 1; a = pxn; b = dy > 0.f ? pzn : -pzn; }
  float uu = fminf(fmaxf((a + 1.f) * 0.5f * 255.f, 0.f), 255.f);
  float vv = fminf(fmaxf((b + 1.f) * 0.5f * 255.f, 0.f), 255.f);

  const long outbase = ((long)((yy + 1) * WP + xx + 1)) << 8;
  const int c0 = (lane >> 1) << 3;     // channel octet
  const int up = lane & 1;             // 0 -> u0, 1 -> u1
  const int slot = (face == 0) ? 0 : (face == 1) ? 1 : (face == 5) ? 2 : -1;

  if (slot < 0) {                      // faces 2/3/4 are the zero 'emptyFace'
    if (!up) *(uint4*)&Xp[outbase + c0] = make_uint4(0u, 0u, 0u, 0u);
    return;
  }
  int u0 = (int)uu, v0 = (int)vv;
  int u1 = min(u0 + 1, 255), v1 = min(v0 + 1, 255);
  float wu = uu - (float)u0, wv = vv - (float)v0;
  int uc = up ? u1 : u0;
  float wA = up ? wu : (1.f - wu);
  const __hip_bfloat16* base = Ft + ((long)slot << 24);  // slot * 65536 * 256

  float acc[8] = {0.f, 0.f, 0.f, 0.f, 0.f, 0.f, 0.f, 0.f};
  uint4 q0 = *(const uint4*)&base[(((long)(v0 << 8) + uc) << 8) + c0];
  uint4 q1 = *(const uint4*)&base[(((long)(v1 << 8) + uc) << 8) + c0];
  bf8_fma(q0, (1.f - wv) * wA, acc);
  bf8_fma(q1, wv * wA, acc);
#pragma unroll
  for (int j = 0; j < 8; ++j) acc[j] += __shfl_xor(acc[j], 1);
  if (!up) {
    union { uint4 q; __hip_bfloat16 h[8]; } o;
#pragma unroll
    for (int j = 0; j < 8; ++j) o.h[j] = __float2bfloat16(acc[j]);
    *(uint4*)&Xp[outbase + c0] = o.q;
  }
}

// ---------------- cube2equi v1 (fallback when ws too small for Ft) -------------
__global__ void aux_gen(const float* __restrict__ fb, const float* __restrict__ fd,
                        const float* __restrict__ fu,
                        __hip_bfloat16* __restrict__ Xp) {
  __shared__ __align__(16) __hip_bfloat16 tile[64 * 264];
  int tid = threadIdx.x;
  int p0 = blockIdx.x * 64;
  int px = tid & 63, w = tid >> 6;

  int p = p0 + px;
  int yy = p >> 9, xx = p & 511;
  float theta = ((xx + 0.5f) / 512.f) * 6.283185307179586f - 3.141592653589793f;
  float phi   = 1.5707963267948966f - ((yy + 0.5f) / 256.f) * 3.141592653589793f;
  float st = sinf(theta), ct = cosf(theta);
  float sp = sinf(phi),   cp = cosf(phi);
  float dx = cp * st, dy = sp, dz = cp * ct;
  float ax = fabsf(dx), ay = fabsf(dy), az = fabsf(dz);
  float mx = fmaxf(fmaxf(ax, ay), az);
  float pxn = dx / mx, pyn = dy / mx, pzn = dz / mx;
  bool cz = (az >= ax) && (az >= ay);
  bool cx = (!cz) && (ax >= ay);
  int face; float a, b;
  if (cz)      { face = dz > 0.f ? 2 : 0; a = dz > 0.f ? pxn : -pxn; b = -pyn; }
  else if (cx) { face = dx > 0.f ? 4 : 3; a = dx > 0.f ? -pzn : pzn; b = -pyn; }
  else         { face = dy > 0.f ? 5 : 1; a = pxn; b = dy > 0.f ? pzn : -pzn; }
  float uu = fminf(fmaxf((a + 1.f) * 0.5f * 255.f, 0.f), 255.f);
  float vv = fminf(fmaxf((b + 1.f) * 0.5f * 255.f, 0.f), 255.f);

  const float* F = (face == 0) ? fb : (face == 1) ? fd : (face == 5) ? fu : nullptr;
  int u0 = (int)uu, v0 = (int)vv;
  int u1 = min(u0 + 1, 255), v1 = min(v0 + 1, 255);
  float wu = uu - (float)u0, wv = vv - (float)v0;
  float w00 = (1.f - wv) * (1.f - wu), w01 = (1.f - wv) * wu;
  float w10 = wv * (1.f - wu),         w11 = wv * wu;
  int i00 = v0 * 256 + u0, i01 = v0 * 256 + u1;
  int i10 = v1 * 256 + u0, i11 = v1 * 256 + u1;
  for (int k = 0; k < 64; ++k) {
    int c = (k << 2) + w;
    float val = 0.f;
    if (F) {
      const float* Fc = F + ((long)c << 16);
      val = w00 * Fc[i00] + w01 * Fc[i01] + w10 * Fc[i10] + w11 * Fc[i11];
    }
    tile[px * 264 + c] = __float2bfloat16(val);
  }
  __syncthreads();
  int y = p0 >> 9, x0g = p0 & 511;
  long basep = (long)(y + 1) * WP + x0g + 1;
  for (int pass = 0; pass < 8; ++pass) {
    int tpx = (pass << 3) + (tid >> 5);
    int chunk = tid & 31;
    uint4 v = *(const uint4*)&tile[tpx * 264 + (chunk << 3)];
    *(uint4*)&Xp[(basep + tpx) * 256 + (chunk << 3)] = v;
  }
}

// ---------------- 3x3 conv as implicit GEMM (MFMA bf16) ------------------------
// Tile: 2 pixel rows x 64 cols (M=128) x 128 cout. K-loop: ci-slice outer (8),
// stage 4-row x 80-col x 32-ch halo in LDS once, then 9 taps x 16 MFMA from LDS.
// B fragments: direct global b128 from Wtt (coalesced, L2-resident, no barrier).
// Epilogue: +bias, relu, optional NHWC bf16 store, fused 1x1 mask-dot atomicAdd.
template <bool STORE>
__global__ void conv3x3_mfma(const __hip_bfloat16* __restrict__ Xp,
                             const __hip_bfloat16* __restrict__ Wtt,
                             const float* __restrict__ bias,
                             const float* __restrict__ wm,
                             __hip_bfloat16* __restrict__ Out,
                             float* __restrict__ maskacc) {
  __shared__ __align__(16) __hip_bfloat16 At[4 * 80 * 32];   // 20480 B halo
  const int tid = threadIdx.x;
  const int wave = tid >> 6, lane = tid & 63;
  const int bx = blockIdx.x;
  const int n0 = (bx & 1) << 7;        // cout half
  const int tile = bx >> 1;            // 0..1023
  const int x0 = (tile >> 7) << 6;     // col strip (8 strips of 64)
  const int y0 = (tile & 127) << 1;    // row pair (rows vary fastest -> halo reuse)
  const int wrow = wave >> 1;          // this wave's pixel row within tile (0/1)
  const int n_off = (wave & 1) << 6;   // this wave's cout offset (0/64)
  const int lq = lane >> 4, ln = lane & 15;

  // halo staging: wave stages padded row (y0 + wave), cols x0 .. x0+79
  const long stage_row = (long)(y0 + wave) * WP + x0;
  const int s_col = lane >> 2;           // 0..15
  const int s_ci  = (lane & 3) << 3;     // 0,8,16,24

  f32x4 acc[4][4] = {};   // [mi (16-px col group)][ni (16-cout group)]

  for (int s = 0; s < 8; ++s) {
    const int ci0 = s << 5;
#pragma unroll
    for (int j = 0; j < 5; ++j) {
      const __hip_bfloat16* gp = Xp + ((stage_row + (j << 4) + s_col) << 8) + ci0 + s_ci;
      async16(gp, &At[(wave * 80 + (j << 4)) << 5]);
    }
    __syncthreads();   // drains vmcnt -> staged halo visible
#pragma unroll
    for (int o = 0; o < 9; ++o) {
      const int dy = o / 3, dxo = o % 3;
      const int arow = (wrow + dy) * 80;
      bf16x8 af[4], bb[4];
#pragma unroll
      for (int mi = 0; mi < 4; ++mi)
        af[mi] = *(const bf16x8*)&At[((arow + mi * 16 + ln + dxo) << 5) + (lq << 3)];
#pragma unroll
      for (int ni = 0; ni < 4; ++ni)
        bb[ni] = *(const bf16x8*)&Wtt[(((o << 5) + (s << 2) + lq) << 11) +
                                      ((n0 + n_off + ni * 16 + ln) << 3)];
#pragma unroll
      for (int mi = 0; mi < 4; ++mi)
#pragma unroll
        for (int ni = 0; ni < 4; ++ni)
          acc[mi][ni] = __builtin_amdgcn_mfma_f32_16x16x32_bf16(af[mi], bb[ni], acc[mi][ni], 0, 0, 0);
    }
    __syncthreads();   // protect At before next slice's staging
  }

  // epilogue: bias + relu (+store NHWC bf16) + fused mask 1x1 dot
  float bv[4], wv[4];
#pragma unroll
  for (int ni = 0; ni < 4; ++ni) {
    int cc = n0 + n_off + ni * 16 + ln;
    bv[ni] = bias[cc];
    wv[ni] = wm[cc];
  }
  const int prow = (y0 + wrow) * 512 + x0;
#pragma unroll
  for (int mi = 0; mi < 4; ++mi) {
#pragma unroll
    for (int r = 0; r < 4; ++r) {
      int pix = prow + mi * 16 + (lq << 2) + r;   // D row = pixel col within tile
      float mp = 0.f;
#pragma unroll
      for (int ni = 0; ni < 4; ++ni) {
        float v = acc[mi][ni][r] + bv[ni];
        v = v > 0.f ? v : 0.f;
        if (STORE) Out[((long)pix << 8) + (n0 + n_off + ni * 16 + ln)] = __float2bfloat16(v);
        mp += v * wv[ni];
      }
      mp += __shfl_xor(mp, 1);
      mp += __shfl_xor(mp, 2);
      mp += __shfl_xor(mp, 4);
      mp += __shfl_xor(mp, 8);
      if (ln == 0) atomicAdd(&maskacc[pix], mp);
    }
  }
}

// ---------------- mask sigmoid + final combine ---------------------------------
__global__ void mask_sigmoid(float* maskacc, const float* __restrict__ bm) {
  int i = blockIdx.x * 256 + threadIdx.x;
  float v = maskacc[i] + bm[0];
  maskacc[i] = 1.f / (1.f + expf(-v));
}

// out[c][p] = m[c][p] + mask[p] * M_aux_t[p][c]; aux transposed through LDS
__global__ void final_combine(const float* __restrict__ m,
                              const __hip_bfloat16* __restrict__ MauxT,
                              const float* __restrict__ mask,
                              float* __restrict__ out) {
  __shared__ __align__(16) __hip_bfloat16 tile[64 * 264];
  __shared__ float sm[64];
  int tid = threadIdx.x;
  int p0 = blockIdx.x * 64;
  if (tid < 64) sm[tid] = mask[p0 + tid];
#pragma unroll
  for (int j = 0; j < 8; ++j) {       // stage 64 px x 256 ch, coalesced uint4
    int f = j * 256 + tid;            // 0..2047
    int px = f >> 5, c8 = f & 31;
    *(uint4*)&tile[px * 264 + (c8 << 3)] =
        *(const uint4*)&MauxT[(((long)(p0 + px)) << 8) + (c8 << 3)];
  }
  __syncthreads();
  int px = tid & 63, w = tid >> 6;
  float mk = sm[px];
  for (int k = 0; k < 64; ++k) {
    int c = (k << 2) + w;
    long gi = (long)c * NPIX + p0 + px;
    out[gi] = m[gi] + mk * __bfloat162float(tile[px * 264 + c]);
  }
}

extern "C" void kernel_launch(void* const* d_in, const int* in_sizes, int n_in,
                              void* d_out, int out_size, void* d_ws, size_t ws_size,
                              hipStream_t stream) {
  const float* m  = (const float*)d_in[0];
  const float* fb = (const float*)d_in[1];  // face 0 (back)
  const float* fu = (const float*)d_in[2];  // face 5 (up)
  const float* fd = (const float*)d_in[3];  // face 1 (down)
  const float* Wf = (const float*)d_in[4];
  const float* bf = (const float*)d_in[5];
  const float* Wm = (const float*)d_in[6];
  const float* bm = (const float*)d_in[7];
  float* out = (float*)d_out;

  char* ws = (char*)d_ws;
  // Fast path layout (Ft aliases the Xp_m region; Ft is dead before nchw writes):
  //   [0, FT_BYTES)                 : Ft, then Xp_m (XP_STRIDE <= FT_BYTES)
  //   [FT_BYTES, +XP_STRIDE)        : Xp_aux
  //   then Wtt (1179648), MauxT (67108864), maskacc (524288)
  const size_t NEED_FAST = (size_t)FT_BYTES + XP_STRIDE + 1179648 + 67108864 + 524288; // 237,438,976

  if (ws_size >= NEED_FAST) {
    __hip_bfloat16* Ft     = (__hip_bfloat16*)(ws);
    __hip_bfloat16* Xp_m   = (__hip_bfloat16*)(ws);                       // aliases Ft (after Ft dead)
    __hip_bfloat16* Xp_aux = (__hip_bfloat16*)(ws + (size_t)FT_BYTES);
    __hip_bfloat16* Wtt    = (__hip_bfloat16*)(ws + (size_t)FT_BYTES + XP_STRIDE);
    __hip_bfloat16* MauxT  = (__hip_bfloat16*)(ws + (size_t)FT_BYTES + XP_STRIDE + 1179648);
    float* maskacc         = (float*)(ws + (size_t)FT_BYTES + XP_STRIDE + 1179648 + 67108864);

    face_to_nhwc<<<3072, 256, 0, stream>>>(fb, fd, fu, Ft);
    aux_gen_v2<<<32768, 256, 0, stream>>>(Ft, Xp_aux);      // Ft dead after this
    nchw_to_pad_nhwc<<<2048, 256, 0, stream>>>(m, Xp_m);    // overwrites Ft region
    zero_borders<<<dim3(1540, 2), 128, 0, stream>>>(Xp_m, Xp_aux);
    prep_weights<<<2304, 256, 0, stream>>>(Wf, Wtt);
    zero_mask<<<512, 256, 0, stream>>>(maskacc);
    conv3x3_mfma<true><<<2048, 256, 0, stream>>>(Xp_aux, Wtt, bf, Wm + 256, MauxT, maskacc);
    conv3x3_mfma<false><<<2048, 256, 0, stream>>>(Xp_m, Wtt, bf, Wm, nullptr, maskacc);
    mask_sigmoid<<<512, 256, 0, stream>>>(maskacc, bm);
    final_combine<<<2048, 256, 0, stream>>>(m, MauxT, maskacc, out);
  } else {
    // Fallback: round-2 layout (~195.3 MiB), planar gather aux_gen
    __hip_bfloat16* Xp_m   = (__hip_bfloat16*)(ws);
    __hip_bfloat16* Xp_aux = (__hip_bfloat16*)(ws + (size_t)XP_STRIDE);
    __hip_bfloat16* Wtt    = (__hip_bfloat16*)(ws + 2uL * XP_STRIDE);
    __hip_bfloat16* MauxT  = (__hip_bfloat16*)(ws + 2uL * XP_STRIDE + 1179648);
    float* maskacc         = (float*)(ws + 2uL * XP_STRIDE + 1179648 + 67108864);

    zero_borders<<<dim3(1540, 2), 128, 0, stream>>>(Xp_m, Xp_aux);
    zero_mask<<<512, 256, 0, stream>>>(maskacc);
    prep_weights<<<2304, 256, 0, stream>>>(Wf, Wtt);
    nchw_to_pad_nhwc<<<2048, 256, 0, stream>>>(m, Xp_m);
    aux_gen<<<2048, 256, 0, stream>>>(fb, fd, fu, Xp_aux);
    conv3x3_mfma<true><<<2048, 256, 0, stream>>>(Xp_aux, Wtt, bf, Wm + 256, MauxT, maskacc);
    conv3x3_mfma<false><<<2048, 256, 0, stream>>>(Xp_m, Wtt, bf, Wm, nullptr, maskacc);
    mask_sigmoid<<<512, 256, 0, stream>>>(maskacc, bm);
    final_combine<<<2048, 256, 0, stream>>>(m, MauxT, maskacc, out);
  }
}